// Round 5
// baseline (634.359 us; speedup 1.0000x reference)
//
#include <hip/hip_runtime.h>
#include <hip/hip_bf16.h>

using bf16 = __hip_bfloat16;
typedef __attribute__((ext_vector_type(8))) short short8;
typedef __attribute__((ext_vector_type(4))) float floatx4;

#define NN 50000
#define EE 800000
#define DD 128
#define HH 8
#define CC 16
#define EDD 32
#define DF 512
#define NQC 64      // partitioned queue counters
#define PART 782    // ceil(NN/NQC)

__device__ __forceinline__ float b2f(bf16 v) { return __bfloat162float(v); }
__device__ __forceinline__ float bs2f(short s) {
    bf16 h = *reinterpret_cast<bf16*>(&s);
    return __bfloat162float(h);
}
__device__ __forceinline__ float bu2f(unsigned short s) {
    unsigned int u = ((unsigned int)s) << 16;
    return *reinterpret_cast<float*>(&u);
}
__device__ __forceinline__ short f2bs(float v) {
    bf16 h = __float2bfloat16(v);
    return *reinterpret_cast<short*>(&h);
}

__device__ __forceinline__ int clampn(int v)
{
    return (v < 0) ? 0 : (v >= NN ? NN - 1 : v);
}

// ---- pack ALL fp32 weights [K][N] into per-lane MFMA B-frag layout (bf16) ----
// + block 784 thread 0: edge_index width detection (int64 has zero high-words)
__global__ void k_packall(const float* __restrict__ Wq, const float* __restrict__ Wk,
                          const float* __restrict__ Wv, const float* __restrict__ Wsk,
                          const float* __restrict__ W1, const float* __restrict__ W2,
                          const float* __restrict__ We,
                          bf16* __restrict__ wqp, bf16* __restrict__ wkp,
                          bf16* __restrict__ wvp, bf16* __restrict__ wskp,
                          bf16* __restrict__ w1p, bf16* __restrict__ w2p,
                          bf16* __restrict__ wep,
                          const int* __restrict__ ei, int* __restrict__ flag)
{
    int idx = blockIdx.x * 256 + threadIdx.x;
    const float* W; bf16* out; int ksteps, N, local;
    if (idx < 65536) {
        int wsel = idx >> 14; local = idx & 16383;
        W   = (wsel == 0) ? Wq  : (wsel == 1) ? Wk  : (wsel == 2) ? Wv  : Wsk;
        out = (wsel == 0) ? wqp : (wsel == 1) ? wkp : (wsel == 2) ? wvp : wskp;
        ksteps = 4; N = 128;
    } else if (idx < 131072) { local = idx - 65536;  W = W1; out = w1p; ksteps = 4;  N = 512; }
    else if (idx < 196608)   { local = idx - 131072; W = W2; out = w2p; ksteps = 16; N = 128; }
    else if (idx < 200704)   { local = idx - 196608; W = We; out = wep; ksteps = 1;  N = 128; }
    else {
        if (idx == 200704) {   // block 784, thread 0: detect
            int all0 = 1;
            for (int i = 0; i < 16; ++i) all0 &= (ei[2 * i + 1] == 0);
            flag[0] = all0;    // 1 => int64 layout, 0 => int32
        }
        return;
    }
    int j = local & 7, lane = (local >> 3) & 63, rest = local >> 9;
    int kstep = rest % ksteps, ntile = rest / ksteps;
    int quad = lane >> 4, m = lane & 15;
    int k = kstep * 32 + quad * 8 + j;
    int n = ntile * 16 + m;
    out[local] = __float2bfloat16(W[(size_t)k * N + n]);
}

// ---------------- projections via MFMA: q, k|v packed, skip ----------------
__global__ __launch_bounds__(256) void k_proj(
    const float* __restrict__ x,
    const bf16* __restrict__ wqp, const bf16* __restrict__ wkp,
    const bf16* __restrict__ wvp, const bf16* __restrict__ wskp,
    const float* __restrict__ bq, const float* __restrict__ bk,
    const float* __restrict__ bv, const float* __restrict__ bsk,
    bf16* __restrict__ qb, unsigned int* __restrict__ kvb,
    bf16* __restrict__ skipb)
{
    __shared__ __align__(16) short xs[32][136];
    __shared__ __align__(16) short os[32][520];
    const int t = threadIdx.x;
    const int wave = t >> 6, lane = t & 63;
    const int quad = lane >> 4, m = lane & 15;
    const int n0 = blockIdx.x * 32;

    for (int idx = t; idx < 32 * 32; idx += 256) {
        int row = idx >> 5, g = idx & 31;
        int node = n0 + row;
        float4 xv = {0.f, 0.f, 0.f, 0.f};
        if (node < NN) xv = *reinterpret_cast<const float4*>(&x[(size_t)node * 128 + g * 4]);
        short4 s4;
        s4.x = f2bs(xv.x); s4.y = f2bs(xv.y); s4.z = f2bs(xv.z); s4.w = f2bs(xv.w);
        *reinterpret_cast<short4*>(&xs[row][g * 4]) = s4;
    }
    __syncthreads();

    const bf16* Wp = (wave == 0) ? wqp : (wave == 1) ? wkp : (wave == 2) ? wvp : wskp;
    const float* bias = (wave == 0) ? bq : (wave == 1) ? bk : (wave == 2) ? bv : bsk;

    floatx4 acc[2][8];
#pragma unroll
    for (int mt = 0; mt < 2; ++mt)
#pragma unroll
        for (int nt = 0; nt < 8; ++nt) acc[mt][nt] = (floatx4){0.f, 0.f, 0.f, 0.f};

#pragma unroll
    for (int kstep = 0; kstep < 4; ++kstep) {
        short8 af0 = *reinterpret_cast<const short8*>(&xs[m][kstep * 32 + quad * 8]);
        short8 af1 = *reinterpret_cast<const short8*>(&xs[16 + m][kstep * 32 + quad * 8]);
#pragma unroll
        for (int nt = 0; nt < 8; ++nt) {
            short8 bf = *reinterpret_cast<const short8*>(
                reinterpret_cast<const short*>(Wp) + ((nt * 4 + kstep) * 64 + lane) * 8);
            acc[0][nt] = __builtin_amdgcn_mfma_f32_16x16x32_bf16(af0, bf, acc[0][nt], 0, 0, 0);
            acc[1][nt] = __builtin_amdgcn_mfma_f32_16x16x32_bf16(af1, bf, acc[1][nt], 0, 0, 0);
        }
    }
#pragma unroll
    for (int nt = 0; nt < 8; ++nt) {
        float bs = bias[nt * 16 + m];
#pragma unroll
        for (int mt = 0; mt < 2; ++mt)
#pragma unroll
            for (int r = 0; r < 4; ++r)
                os[mt * 16 + quad * 4 + r][wave * 128 + nt * 16 + m] = f2bs(acc[mt][nt][r] + bs);
    }
    __syncthreads();
    // output: q (bf16), skip (bf16), kv packed as uint (k low16 | v high16)
    for (int idx = t; idx < 32 * 64; idx += 256) {
        int row = idx >> 6, c = idx & 63;
        int node = n0 + row;
        if (node >= NN) continue;
        unsigned int qu  = *reinterpret_cast<const unsigned int*>(&os[row][2 * c]);
        unsigned int ku  = *reinterpret_cast<const unsigned int*>(&os[row][128 + 2 * c]);
        unsigned int vu  = *reinterpret_cast<const unsigned int*>(&os[row][256 + 2 * c]);
        unsigned int sku = *reinterpret_cast<const unsigned int*>(&os[row][384 + 2 * c]);
        reinterpret_cast<unsigned int*>(qb)[(size_t)node * 64 + c] = qu;
        reinterpret_cast<unsigned int*>(skipb)[(size_t)node * 64 + c] = sku;
        uint2 kv;
        kv.x = (ku & 0xffffu) | (vu << 16);          // ch 2c  : k|v
        kv.y = (ku >> 16) | (vu & 0xffff0000u);      // ch 2c+1: k|v
        reinterpret_cast<uint2*>(kvb)[(size_t)node * 64 + c] = kv;
    }
}

// ---------------- CSR build ----------------
__global__ void k_hist(const int* __restrict__ ei, const int* __restrict__ flag,
                       int* __restrict__ deg)
{
    int tt = blockIdx.x * 256 + threadIdx.x;
    int i0 = tt * 2;
    if (i0 >= EE) return;
    int d0, d1;
    if (flag[0]) {
        int4 v = *reinterpret_cast<const int4*>(&ei[2 * EE + 2 * i0]);
        d0 = v.x; d1 = v.z;
    } else {
        int2 v = *reinterpret_cast<const int2*>(&ei[EE + i0]);
        d0 = v.x; d1 = v.y;
    }
    atomicAdd(&deg[clampn(d0)], 1);
    atomicAdd(&deg[clampn(d1)], 1);
}

__global__ __launch_bounds__(1024) void k_scan(const int* __restrict__ deg,
                                               int* __restrict__ rowstart)
{
    __shared__ int s[1024];
    const int t = threadIdx.x;
    const int CH = 49;
    int base = t * CH;
    int sum = 0;
    for (int i = 0; i < CH; i++) {
        int idx = base + i;
        if (idx < NN) sum += deg[idx];
    }
    s[t] = sum;
    __syncthreads();
    int own = sum;
    for (int off = 1; off < 1024; off <<= 1) {
        int v = (t >= off) ? s[t - off] : 0;
        __syncthreads();
        s[t] += v;
        __syncthreads();
    }
    int run = s[t] - own;
    for (int i = 0; i < CH; i++) {
        int idx = base + i;
        if (idx < NN) {
            rowstart[idx] = run;
            run += deg[idx];
        }
    }
    if (t == 0) rowstart[NN] = EE;
}

// scatter + fused edge_attr gather: CSR-ordered bf16 edge rows (64B each)
__global__ void k_scatter(const int* __restrict__ ei, const int* __restrict__ flag,
                          const int* __restrict__ rowstart,
                          int* __restrict__ cursor, int* __restrict__ srcs,
                          const float* __restrict__ ea,
                          short* __restrict__ eacsr)
{
    int i = blockIdx.x * 256 + threadIdx.x;
    if (i >= EE) return;
    int is64 = flag[0];
    int d = clampn(is64 ? ei[2 * EE + 2 * i] : ei[EE + i]);
    int s = clampn(is64 ? ei[2 * i] : ei[i]);
    int pos = rowstart[d] + atomicAdd(&cursor[d], 1);
    __builtin_nontemporal_store(s, &srcs[pos]);
    const float4* er = reinterpret_cast<const float4*>(ea + (size_t)i * 32);
    short8* dst = reinterpret_cast<short8*>(eacsr + (size_t)pos * 32);
#pragma unroll
    for (int g = 0; g < 4; ++g) {
        float4 a = er[2 * g], b = er[2 * g + 1];
        short8 o;
        o[0] = f2bs(a.x); o[1] = f2bs(a.y); o[2] = f2bs(a.z); o[3] = f2bs(a.w);
        o[4] = f2bs(b.x); o[5] = f2bs(b.y); o[6] = f2bs(b.z); o[7] = f2bs(b.w);
        __builtin_nontemporal_store(o, &dst[g]);
    }
}

// -------- fused attention: PERSISTENT WAVES, 64 partitioned queue counters --------
// block = 256 threads = 4 waves; wave g pops node batches (4) from counter g&63.
// lane owns channels 2*lane, 2*lane+1 (head = lane>>3, 8 lanes per head).
__global__ __launch_bounds__(256) void k_attn(
    const float* __restrict__ x,
    const short* __restrict__ eacsr, const bf16* __restrict__ wep,
    const bf16* __restrict__ qb, const unsigned int* __restrict__ kvb,
    const bf16* __restrict__ skipb,
    const int* __restrict__ rowstart, const int* __restrict__ srcs,
    const float* __restrict__ ln1g, const float* __restrict__ ln1b,
    int* __restrict__ qcounter, bf16* __restrict__ hb)
{
    // es transposed: [channel][edge] with stride 18 shorts (36B) per channel row
    __shared__ __align__(16) short es[4][128][18];
    __shared__ __align__(16) short wes[4096];
    const int t = threadIdx.x;
    const int wave = t >> 6, lane = t & 63;
    const int quad = lane >> 4, m = lane & 15;

    // stage We fragments once per block (8 ntiles x 64 lanes x 8 bf16 = 8KB)
    for (int idx = t; idx < 512; idx += 256)
        *reinterpret_cast<short8*>(&wes[idx * 8]) =
            *reinterpret_cast<const short8*>(reinterpret_cast<const short*>(wep) + idx * 8);
    __syncthreads();   // only barrier in the kernel

    short (*esw)[18] = es[wave];
    const float QS = 0.3606737602f;   // 0.25 * log2(e)

    const int gw = blockIdx.x * 4 + wave;
    const int c  = gw & (NQC - 1);
    const int base = c * PART;
    const int cnt_c = (NN - base < PART) ? (NN - base) : PART;
    int* qc = qcounter + c * 16;   // 64B stride: one counter per cacheline

    for (;;) {
        int nl;
        if (lane == 0) nl = atomicAdd(qc, 4);
        nl = __builtin_amdgcn_readfirstlane(nl);
        if (nl >= cnt_c) break;
        const int nhi = (nl + 4 < cnt_c) ? nl + 4 : cnt_c;

        for (int ni = nl; ni < nhi; ++ni) {
            const int n = base + ni;

            unsigned int qp = reinterpret_cast<const unsigned int*>(qb)[(size_t)n * 64 + lane];
            float q0 = bu2f((unsigned short)(qp & 0xffffu)) * QS;
            float q1 = bu2f((unsigned short)(qp >> 16)) * QS;

            const int eoff = rowstart[n], eend = rowstart[n + 1];
            float lsum = 0.f, acc0 = 0.f, acc1 = 0.f;

            for (int p0 = eoff; p0 < eend; p0 += 16) {
                int pos = p0 + m;
                int pc = (pos < eend) ? pos : eoff;
                int sj_all = srcs[pc];   // lane m holds src for tile edge m

                // A-frag: direct bf16 load from CSR-ordered edge rows (16B/lane)
                short8 Af = *reinterpret_cast<const short8*>(eacsr + (size_t)pc * 32 + quad * 8);

                // kv prefetch: 16 coalesced 8B loads, SGPR row base via readlane
                uint2 kvr[16];
#pragma unroll
                for (int j = 0; j < 16; ++j) {
                    int sj = __builtin_amdgcn_readlane(sj_all, j);
                    kvr[j] = reinterpret_cast<const uint2*>(kvb + (size_t)(unsigned)sj * 128)[lane];
                }

#pragma unroll
                for (int nt = 0; nt < 8; ++nt) {
                    short8 Bf = *reinterpret_cast<const short8*>(&wes[(nt * 64 + lane) * 8]);
                    floatx4 C = {0.f, 0.f, 0.f, 0.f};
                    C = __builtin_amdgcn_mfma_f32_16x16x32_bf16(Af, Bf, C, 0, 0, 0);
                    int col = nt * 16 + m;
                    unsigned int d0 = (unsigned int)(unsigned short)f2bs(C[0]) |
                                      ((unsigned int)(unsigned short)f2bs(C[1]) << 16);
                    unsigned int d1 = (unsigned int)(unsigned short)f2bs(C[2]) |
                                      ((unsigned int)(unsigned short)f2bs(C[3]) << 16);
                    unsigned int* p = reinterpret_cast<unsigned int*>(&esw[col][quad * 4]);
                    p[0] = d0; p[1] = d1;   // edges quad*4..quad*4+3 of channel col
                }
                __builtin_amdgcn_wave_barrier();   // wave-local LDS: writes before reads

                // batch-read e for this lane's 2 channels, all 16 edges -> registers
                unsigned int ear[8], ebr[8];
                {
                    const unsigned int* ra = reinterpret_cast<const unsigned int*>(&esw[2 * lane][0]);
                    const unsigned int* rb = reinterpret_cast<const unsigned int*>(&esw[2 * lane + 1][0]);
#pragma unroll
                    for (int jj = 0; jj < 8; ++jj) { ear[jj] = ra[jj]; ebr[jj] = rb[jj]; }
                }

                int cnt = eend - p0; if (cnt > 16) cnt = 16;
#pragma unroll
                for (int j = 0; j < 16; ++j) {
                    unsigned int eva = ear[j >> 1], evb = ebr[j >> 1];
                    float e0 = (j & 1) ? bu2f((unsigned short)(eva >> 16))
                                       : bu2f((unsigned short)(eva & 0xffffu));
                    float e1 = (j & 1) ? bu2f((unsigned short)(evb >> 16))
                                       : bu2f((unsigned short)(evb & 0xffffu));
                    float k0 = bu2f((unsigned short)(kvr[j].x & 0xffffu));
                    float v0 = bu2f((unsigned short)(kvr[j].x >> 16));
                    float k1 = bu2f((unsigned short)(kvr[j].y & 0xffffu));
                    float v1 = bu2f((unsigned short)(kvr[j].y >> 16));
                    float pr = fmaf(k1 + e1, q1, (k0 + e0) * q0);   // pre-scaled by 0.25*log2e
                    // 3-level xor butterfly over the 8-lane head group (BitMode swizzle)
                    pr += __int_as_float(__builtin_amdgcn_ds_swizzle(__float_as_int(pr), 0x041F));
                    pr += __int_as_float(__builtin_amdgcn_ds_swizzle(__float_as_int(pr), 0x081F));
                    pr += __int_as_float(__builtin_amdgcn_ds_swizzle(__float_as_int(pr), 0x101F));
                    float w = (j < cnt) ? __builtin_amdgcn_exp2f(pr) : 0.f;
                    lsum += w;
                    acc0 = fmaf(v0 + e0, w, acc0);
                    acc1 = fmaf(v1 + e1, w, acc1);
                }
                __builtin_amdgcn_wave_barrier();   // reads before next tile's writes
            }

            float rden = 1.f / (lsum + 1e-16f);
            float attn0 = acc0 * rden, attn1 = acc1 * rden;
            float2 xv = *reinterpret_cast<const float2*>(x + (size_t)n * 128 + 2 * lane);
            unsigned int skp = reinterpret_cast<const unsigned int*>(skipb)[(size_t)n * 64 + lane];
            float pre0 = xv.x + attn0 + bu2f((unsigned short)(skp & 0xffffu));
            float pre1 = xv.y + attn1 + bu2f((unsigned short)(skp >> 16));
            float s1 = pre0 + pre1, s2 = pre0 * pre0 + pre1 * pre1;
#pragma unroll
            for (int off = 1; off < 64; off <<= 1) {
                s1 += __shfl_xor(s1, off);
                s2 += __shfl_xor(s2, off);
            }
            float mu = s1 * (1.f / 128.f);
            float var = s2 * (1.f / 128.f) - mu * mu;
            float inv = rsqrtf(var + 1e-5f);
            float2 g  = *reinterpret_cast<const float2*>(ln1g + 2 * lane);
            float2 bb = *reinterpret_cast<const float2*>(ln1b + 2 * lane);
            float h0 = (pre0 - mu) * inv * g.x + bb.x;
            float h1 = (pre1 - mu) * inv * g.y + bb.y;
            unsigned int hu = (unsigned int)(unsigned short)f2bs(h0) |
                              ((unsigned int)(unsigned short)f2bs(h1) << 16);
            reinterpret_cast<unsigned int*>(hb)[(size_t)n * 64 + lane] = hu;
        }
    }
}

// ---------------- FFN via MFMA + LN2 ----------------
__global__ __launch_bounds__(256) void k_ffn(
    const bf16* __restrict__ hb,
    const bf16* __restrict__ w1p, const float* __restrict__ b1,
    const bf16* __restrict__ w2p, const float* __restrict__ b2,
    const float* __restrict__ ln2g, const float* __restrict__ ln2b,
    float* __restrict__ out)
{
    __shared__ __align__(16) short hs[32][136];
    __shared__ __align__(16) short t1s[32][520];
    float* fs = reinterpret_cast<float*>(&t1s[0][0]);  // [32][132] after t1s is dead
    const int t = threadIdx.x;
    const int wave = t >> 6, lane = t & 63;
    const int quad = lane >> 4, m = lane & 15;
    const int n0 = blockIdx.x * 32;

    for (int idx = t; idx < 32 * 16; idx += 256) {
        int row = idx >> 4, g = idx & 15;
        int node = n0 + row;
        if (node < NN) {
            *reinterpret_cast<float4*>(&hs[row][g * 8]) =
                *reinterpret_cast<const float4*>(&hb[(size_t)node * 128 + g * 8]);
        } else {
            float4 z = {0.f, 0.f, 0.f, 0.f};
            *reinterpret_cast<float4*>(&hs[row][g * 8]) = z;
        }
    }
    __syncthreads();

    floatx4 acc1[2][8];
#pragma unroll
    for (int mt = 0; mt < 2; ++mt)
#pragma unroll
        for (int nt = 0; nt < 8; ++nt) acc1[mt][nt] = (floatx4){0.f, 0.f, 0.f, 0.f};
#pragma unroll
    for (int kstep = 0; kstep < 4; ++kstep) {
        short8 af0 = *reinterpret_cast<const short8*>(&hs[m][kstep * 32 + quad * 8]);
        short8 af1 = *reinterpret_cast<const short8*>(&hs[16 + m][kstep * 32 + quad * 8]);
#pragma unroll
        for (int nt = 0; nt < 8; ++nt) {
            short8 bf = *reinterpret_cast<const short8*>(
                reinterpret_cast<const short*>(w1p) + (((wave * 8 + nt) * 4 + kstep) * 64 + lane) * 8);
            acc1[0][nt] = __builtin_amdgcn_mfma_f32_16x16x32_bf16(af0, bf, acc1[0][nt], 0, 0, 0);
            acc1[1][nt] = __builtin_amdgcn_mfma_f32_16x16x32_bf16(af1, bf, acc1[1][nt], 0, 0, 0);
        }
    }
#pragma unroll
    for (int nt = 0; nt < 8; ++nt) {
        float bs = b1[wave * 128 + nt * 16 + m];
#pragma unroll
        for (int mt = 0; mt < 2; ++mt)
#pragma unroll
            for (int r = 0; r < 4; ++r)
                t1s[mt * 16 + quad * 4 + r][wave * 128 + nt * 16 + m] =
                    f2bs(fmaxf(acc1[mt][nt][r] + bs, 0.f));
    }
    __syncthreads();

    floatx4 acc2[2][2];
#pragma unroll
    for (int mt = 0; mt < 2; ++mt)
#pragma unroll
        for (int nt = 0; nt < 2; ++nt) acc2[mt][nt] = (floatx4){0.f, 0.f, 0.f, 0.f};
#pragma unroll
    for (int kstep = 0; kstep < 16; ++kstep) {
        short8 af0 = *reinterpret_cast<const short8*>(&t1s[m][kstep * 32 + quad * 8]);
        short8 af1 = *reinterpret_cast<const short8*>(&t1s[16 + m][kstep * 32 + quad * 8]);
#pragma unroll
        for (int nt = 0; nt < 2; ++nt) {
            short8 bf = *reinterpret_cast<const short8*>(
                reinterpret_cast<const short*>(w2p) + (((wave * 2 + nt) * 16 + kstep) * 64 + lane) * 8);
            acc2[0][nt] = __builtin_amdgcn_mfma_f32_16x16x32_bf16(af0, bf, acc2[0][nt], 0, 0, 0);
            acc2[1][nt] = __builtin_amdgcn_mfma_f32_16x16x32_bf16(af1, bf, acc2[1][nt], 0, 0, 0);
        }
    }
    __syncthreads();
#pragma unroll
    for (int nt = 0; nt < 2; ++nt) {
        int col = (wave * 2 + nt) * 16 + m;
        float bs = b2[col];
#pragma unroll
        for (int mt = 0; mt < 2; ++mt)
#pragma unroll
            for (int r = 0; r < 4; ++r)
                fs[(mt * 16 + quad * 4 + r) * 132 + col] = acc2[mt][nt][r] + bs;
    }
    __syncthreads();

    for (int rr = 0; rr < 8; ++rr) {
        int row = wave * 8 + rr;
        int node = n0 + row;
        float p0 = bs2f(hs[row][lane]) + fs[row * 132 + lane];
        float p1 = bs2f(hs[row][lane + 64]) + fs[row * 132 + lane + 64];
        float s1 = p0 + p1, s2 = p0 * p0 + p1 * p1;
#pragma unroll
        for (int off = 1; off < 64; off <<= 1) {
            s1 += __shfl_xor(s1, off);
            s2 += __shfl_xor(s2, off);
        }
        float mu = s1 * (1.f / 128.f);
        float var = s2 * (1.f / 128.f) - mu * mu;
        float inv = rsqrtf(var + 1e-5f);
        if (node < NN) {
            float o0 = (p0 - mu) * inv * ln2g[lane] + ln2b[lane];
            float o1 = (p1 - mu) * inv * ln2g[lane + 64] + ln2b[lane + 64];
            __builtin_nontemporal_store(o0, &out[(size_t)node * 128 + lane]);
            __builtin_nontemporal_store(o1, &out[(size_t)node * 128 + lane + 64]);
        }
    }
}

extern "C" void kernel_launch(void* const* d_in, const int* in_sizes, int n_in,
                              void* d_out, int out_size, void* d_ws, size_t ws_size,
                              hipStream_t stream)
{
    const float* x    = (const float*)d_in[0];
    const int*   ei   = (const int*)d_in[1];
    const float* ea   = (const float*)d_in[2];
    const float* Wq   = (const float*)d_in[3];
    const float* bq   = (const float*)d_in[4];
    const float* Wk   = (const float*)d_in[5];
    const float* bk   = (const float*)d_in[6];
    const float* Wv   = (const float*)d_in[7];
    const float* bv   = (const float*)d_in[8];
    const float* We   = (const float*)d_in[9];
    const float* Wsk  = (const float*)d_in[10];
    const float* bsk  = (const float*)d_in[11];
    const float* ln1g = (const float*)d_in[12];
    const float* ln1b = (const float*)d_in[13];
    const float* W1   = (const float*)d_in[14];
    const float* b1   = (const float*)d_in[15];
    const float* W2   = (const float*)d_in[16];
    const float* b2   = (const float*)d_in[17];
    const float* ln2g = (const float*)d_in[18];
    const float* ln2b = (const float*)d_in[19];

    char* ws = (char*)d_ws;
    size_t off = 0;
    auto alloc = [&](size_t bytes) -> void* {
        void* p = ws + off;
        off += (bytes + 255) & ~(size_t)255;
        return p;
    };
    int*   flag     = (int*)alloc(256);
    int*   qcounter = (int*)alloc((size_t)NQC * 16 * 4);   // 64 counters, 64B stride
    int*   deg      = (int*)alloc((size_t)NN * 4);
    int*   cursor   = (int*)alloc((size_t)NN * 4);
    int*   rowstart = (int*)alloc((size_t)(NN + 1) * 4);
    int*   srcs     = (int*)alloc((size_t)EE * 4);
    short* eacsr    = (short*)alloc((size_t)EE * 32 * 2);  // CSR-ordered bf16 edge rows
    bf16*  qb       = (bf16*)alloc((size_t)NN * 128 * 2);
    unsigned int* kvb = (unsigned int*)alloc((size_t)NN * 128 * 4);
    bf16*  skipb    = (bf16*)alloc((size_t)NN * 128 * 2);
    bf16*  hb       = (bf16*)alloc((size_t)NN * 128 * 2);
    bf16*  wqp      = (bf16*)alloc((size_t)16384 * 2);
    bf16*  wkp      = (bf16*)alloc((size_t)16384 * 2);
    bf16*  wvp      = (bf16*)alloc((size_t)16384 * 2);
    bf16*  wskp     = (bf16*)alloc((size_t)16384 * 2);
    bf16*  w1p      = (bf16*)alloc((size_t)65536 * 2);
    bf16*  w2p      = (bf16*)alloc((size_t)65536 * 2);
    bf16*  wep      = (bf16*)alloc((size_t)4096 * 2);

    hipMemsetAsync(deg, 0, (size_t)NN * 4, stream);
    hipMemsetAsync(cursor, 0, (size_t)NN * 4, stream);
    hipMemsetAsync(qcounter, 0, (size_t)NQC * 16 * 4, stream);

    k_packall<<<785, 256, 0, stream>>>(
        Wq, Wk, Wv, Wsk, W1, W2, We, wqp, wkp, wvp, wskp, w1p, w2p, wep, ei, flag);
    k_hist<<<(EE / 2 + 255) / 256, 256, 0, stream>>>(ei, flag, deg);
    k_proj<<<(NN + 31) / 32, 256, 0, stream>>>(x, wqp, wkp, wvp, wskp,
                                               bq, bk, bv, bsk, qb, kvb, skipb);
    k_scan<<<1, 1024, 0, stream>>>(deg, rowstart);
    k_scatter<<<(EE + 255) / 256, 256, 0, stream>>>(ei, flag, rowstart, cursor,
                                                    srcs, ea, eacsr);
    k_attn<<<1536, 256, 0, stream>>>(x, eacsr, wep, qb, kvb, skipb,
                                     rowstart, srcs, ln1g, ln1b, qcounter, hb);
    k_ffn<<<(NN + 31) / 32, 256, 0, stream>>>(hb, w1p, b1, w2p, b2, ln2g, ln2b, (float*)d_out);
}

// Round 6
// 578.752 us; speedup vs baseline: 1.0961x; 1.0961x over previous
//
#include <hip/hip_runtime.h>
#include <hip/hip_bf16.h>

using bf16 = __hip_bfloat16;
typedef __attribute__((ext_vector_type(8))) short short8;
typedef __attribute__((ext_vector_type(4))) float floatx4;

#define NN 50000
#define EE 800000
#define DD 128
#define HH 8
#define CC 16
#define EDD 32
#define DF 512
#define NQC 64      // partitioned queue counters
#define PART 782    // ceil(NN/NQC)

__device__ __forceinline__ float b2f(bf16 v) { return __bfloat162float(v); }
__device__ __forceinline__ float bs2f(short s) {
    bf16 h = *reinterpret_cast<bf16*>(&s);
    return __bfloat162float(h);
}
__device__ __forceinline__ float bu2f(unsigned short s) {
    unsigned int u = ((unsigned int)s) << 16;
    return *reinterpret_cast<float*>(&u);
}
__device__ __forceinline__ short f2bs(float v) {
    bf16 h = __float2bfloat16(v);
    return *reinterpret_cast<short*>(&h);
}

__device__ __forceinline__ int clampn(int v)
{
    return (v < 0) ? 0 : (v >= NN ? NN - 1 : v);
}

// ---- pack ALL fp32 weights [K][N] into per-lane MFMA B-frag layout (bf16) ----
// + block 784 thread 0: edge_index width detection (int64 has zero high-words)
__global__ void k_packall(const float* __restrict__ Wq, const float* __restrict__ Wk,
                          const float* __restrict__ Wv, const float* __restrict__ Wsk,
                          const float* __restrict__ W1, const float* __restrict__ W2,
                          const float* __restrict__ We,
                          bf16* __restrict__ wqp, bf16* __restrict__ wkp,
                          bf16* __restrict__ wvp, bf16* __restrict__ wskp,
                          bf16* __restrict__ w1p, bf16* __restrict__ w2p,
                          bf16* __restrict__ wep,
                          const int* __restrict__ ei, int* __restrict__ flag)
{
    int idx = blockIdx.x * 256 + threadIdx.x;
    const float* W; bf16* out; int ksteps, N, local;
    if (idx < 65536) {
        int wsel = idx >> 14; local = idx & 16383;
        W   = (wsel == 0) ? Wq  : (wsel == 1) ? Wk  : (wsel == 2) ? Wv  : Wsk;
        out = (wsel == 0) ? wqp : (wsel == 1) ? wkp : (wsel == 2) ? wvp : wskp;
        ksteps = 4; N = 128;
    } else if (idx < 131072) { local = idx - 65536;  W = W1; out = w1p; ksteps = 4;  N = 512; }
    else if (idx < 196608)   { local = idx - 131072; W = W2; out = w2p; ksteps = 16; N = 128; }
    else if (idx < 200704)   { local = idx - 196608; W = We; out = wep; ksteps = 1;  N = 128; }
    else {
        if (idx == 200704) {   // block 784, thread 0: detect
            int all0 = 1;
            for (int i = 0; i < 16; ++i) all0 &= (ei[2 * i + 1] == 0);
            flag[0] = all0;    // 1 => int64 layout, 0 => int32
        }
        return;
    }
    int j = local & 7, lane = (local >> 3) & 63, rest = local >> 9;
    int kstep = rest % ksteps, ntile = rest / ksteps;
    int quad = lane >> 4, m = lane & 15;
    int k = kstep * 32 + quad * 8 + j;
    int n = ntile * 16 + m;
    out[local] = __float2bfloat16(W[(size_t)k * N + n]);
}

// ---------------- projections via MFMA: q, k|v packed, skip ----------------
__global__ __launch_bounds__(256) void k_proj(
    const float* __restrict__ x,
    const bf16* __restrict__ wqp, const bf16* __restrict__ wkp,
    const bf16* __restrict__ wvp, const bf16* __restrict__ wskp,
    const float* __restrict__ bq, const float* __restrict__ bk,
    const float* __restrict__ bv, const float* __restrict__ bsk,
    bf16* __restrict__ qb, unsigned int* __restrict__ kvb,
    bf16* __restrict__ skipb)
{
    __shared__ __align__(16) short xs[32][136];
    __shared__ __align__(16) short os[32][520];
    const int t = threadIdx.x;
    const int wave = t >> 6, lane = t & 63;
    const int quad = lane >> 4, m = lane & 15;
    const int n0 = blockIdx.x * 32;

    for (int idx = t; idx < 32 * 32; idx += 256) {
        int row = idx >> 5, g = idx & 31;
        int node = n0 + row;
        float4 xv = {0.f, 0.f, 0.f, 0.f};
        if (node < NN) xv = *reinterpret_cast<const float4*>(&x[(size_t)node * 128 + g * 4]);
        short4 s4;
        s4.x = f2bs(xv.x); s4.y = f2bs(xv.y); s4.z = f2bs(xv.z); s4.w = f2bs(xv.w);
        *reinterpret_cast<short4*>(&xs[row][g * 4]) = s4;
    }
    __syncthreads();

    const bf16* Wp = (wave == 0) ? wqp : (wave == 1) ? wkp : (wave == 2) ? wvp : wskp;
    const float* bias = (wave == 0) ? bq : (wave == 1) ? bk : (wave == 2) ? bv : bsk;

    floatx4 acc[2][8];
#pragma unroll
    for (int mt = 0; mt < 2; ++mt)
#pragma unroll
        for (int nt = 0; nt < 8; ++nt) acc[mt][nt] = (floatx4){0.f, 0.f, 0.f, 0.f};

#pragma unroll
    for (int kstep = 0; kstep < 4; ++kstep) {
        short8 af0 = *reinterpret_cast<const short8*>(&xs[m][kstep * 32 + quad * 8]);
        short8 af1 = *reinterpret_cast<const short8*>(&xs[16 + m][kstep * 32 + quad * 8]);
#pragma unroll
        for (int nt = 0; nt < 8; ++nt) {
            short8 bf = *reinterpret_cast<const short8*>(
                reinterpret_cast<const short*>(Wp) + ((nt * 4 + kstep) * 64 + lane) * 8);
            acc[0][nt] = __builtin_amdgcn_mfma_f32_16x16x32_bf16(af0, bf, acc[0][nt], 0, 0, 0);
            acc[1][nt] = __builtin_amdgcn_mfma_f32_16x16x32_bf16(af1, bf, acc[1][nt], 0, 0, 0);
        }
    }
#pragma unroll
    for (int nt = 0; nt < 8; ++nt) {
        float bs = bias[nt * 16 + m];
#pragma unroll
        for (int mt = 0; mt < 2; ++mt)
#pragma unroll
            for (int r = 0; r < 4; ++r)
                os[mt * 16 + quad * 4 + r][wave * 128 + nt * 16 + m] = f2bs(acc[mt][nt][r] + bs);
    }
    __syncthreads();
    // output: q (bf16), skip (bf16), kv packed as uint (k low16 | v high16)
    for (int idx = t; idx < 32 * 64; idx += 256) {
        int row = idx >> 6, c = idx & 63;
        int node = n0 + row;
        if (node >= NN) continue;
        unsigned int qu  = *reinterpret_cast<const unsigned int*>(&os[row][2 * c]);
        unsigned int ku  = *reinterpret_cast<const unsigned int*>(&os[row][128 + 2 * c]);
        unsigned int vu  = *reinterpret_cast<const unsigned int*>(&os[row][256 + 2 * c]);
        unsigned int sku = *reinterpret_cast<const unsigned int*>(&os[row][384 + 2 * c]);
        reinterpret_cast<unsigned int*>(qb)[(size_t)node * 64 + c] = qu;
        reinterpret_cast<unsigned int*>(skipb)[(size_t)node * 64 + c] = sku;
        uint2 kv;
        kv.x = (ku & 0xffffu) | (vu << 16);          // ch 2c  : k|v
        kv.y = (ku >> 16) | (vu & 0xffff0000u);      // ch 2c+1: k|v
        reinterpret_cast<uint2*>(kvb)[(size_t)node * 64 + c] = kv;
    }
}

// ---------------- CSR build ----------------
__global__ void k_hist(const int* __restrict__ ei, const int* __restrict__ flag,
                       int* __restrict__ deg)
{
    int tt = blockIdx.x * 256 + threadIdx.x;
    int i0 = tt * 2;
    if (i0 >= EE) return;
    int d0, d1;
    if (flag[0]) {
        int4 v = *reinterpret_cast<const int4*>(&ei[2 * EE + 2 * i0]);
        d0 = v.x; d1 = v.z;
    } else {
        int2 v = *reinterpret_cast<const int2*>(&ei[EE + i0]);
        d0 = v.x; d1 = v.y;
    }
    atomicAdd(&deg[clampn(d0)], 1);
    atomicAdd(&deg[clampn(d1)], 1);
}

__global__ __launch_bounds__(1024) void k_scan(const int* __restrict__ deg,
                                               int* __restrict__ rowstart)
{
    __shared__ int s[1024];
    const int t = threadIdx.x;
    const int CH = 49;
    int base = t * CH;
    int sum = 0;
    for (int i = 0; i < CH; i++) {
        int idx = base + i;
        if (idx < NN) sum += deg[idx];
    }
    s[t] = sum;
    __syncthreads();
    int own = sum;
    for (int off = 1; off < 1024; off <<= 1) {
        int v = (t >= off) ? s[t - off] : 0;
        __syncthreads();
        s[t] += v;
        __syncthreads();
    }
    int run = s[t] - own;
    for (int i = 0; i < CH; i++) {
        int idx = base + i;
        if (idx < NN) {
            rowstart[idx] = run;
            run += deg[idx];
        }
    }
    if (t == 0) rowstart[NN] = EE;
}

// scatter: permutation only (two scattered 4B stores through L2)
__global__ void k_scatter(const int* __restrict__ ei, const int* __restrict__ flag,
                          const int* __restrict__ rowstart,
                          int* __restrict__ cursor, int* __restrict__ srcs,
                          int* __restrict__ eids)
{
    int i = blockIdx.x * 256 + threadIdx.x;
    if (i >= EE) return;
    int is64 = flag[0];
    int d = clampn(is64 ? ei[2 * EE + 2 * i] : ei[EE + i]);
    int s = clampn(is64 ? ei[2 * i] : ei[i]);
    int pos = rowstart[d] + atomicAdd(&cursor[d], 1);
    srcs[pos] = s;
    eids[pos] = i;
}

// gather: CSR-sequential edge_attr fetch (random FULL-LINE reads, coalesced writes)
// 4 lanes per edge row: lane j -> row base+(j>>2), quarter j&3 (32B read, 16B write)
__global__ __launch_bounds__(256) void k_gather(
    const int* __restrict__ eids, const float* __restrict__ ea,
    short* __restrict__ eacsr)
{
    int tid = blockIdx.x * 256 + threadIdx.x;
    int pos = tid >> 2, q = tid & 3;
    if (pos >= EE) return;
    int eid = eids[pos];          // 4 lanes same addr -> L1 broadcast
    const float4* er = reinterpret_cast<const float4*>(ea + (size_t)eid * 32 + q * 8);
    float4 a = er[0], b = er[1];
    short8 o;
    o[0] = f2bs(a.x); o[1] = f2bs(a.y); o[2] = f2bs(a.z); o[3] = f2bs(a.w);
    o[4] = f2bs(b.x); o[5] = f2bs(b.y); o[6] = f2bs(b.z); o[7] = f2bs(b.w);
    *reinterpret_cast<short8*>(eacsr + (size_t)pos * 32 + q * 8) = o;
}

// -------- fused attention: PERSISTENT WAVES, 64 partitioned queue counters --------
// block = 256 threads = 4 waves; wave g pops node batches (4) from counter g&63.
// lane owns channels 2*lane, 2*lane+1 (head = lane>>3, 8 lanes per head).
__global__ __launch_bounds__(256) void k_attn(
    const float* __restrict__ x,
    const short* __restrict__ eacsr, const bf16* __restrict__ wep,
    const bf16* __restrict__ qb, const unsigned int* __restrict__ kvb,
    const bf16* __restrict__ skipb,
    const int* __restrict__ rowstart, const int* __restrict__ srcs,
    const float* __restrict__ ln1g, const float* __restrict__ ln1b,
    int* __restrict__ qcounter, bf16* __restrict__ hb)
{
    // es transposed: [channel][edge] with stride 18 shorts (36B) per channel row
    __shared__ __align__(16) short es[4][128][18];
    __shared__ __align__(16) short wes[4096];
    const int t = threadIdx.x;
    const int wave = t >> 6, lane = t & 63;
    const int quad = lane >> 4, m = lane & 15;

    // stage We fragments once per block (8 ntiles x 64 lanes x 8 bf16 = 8KB)
    for (int idx = t; idx < 512; idx += 256)
        *reinterpret_cast<short8*>(&wes[idx * 8]) =
            *reinterpret_cast<const short8*>(reinterpret_cast<const short*>(wep) + idx * 8);
    __syncthreads();   // only barrier in the kernel

    short (*esw)[18] = es[wave];
    const float QS = 0.3606737602f;   // 0.25 * log2(e)

    const int gw = blockIdx.x * 4 + wave;
    const int c  = gw & (NQC - 1);
    const int base = c * PART;
    const int cnt_c = (NN - base < PART) ? (NN - base) : PART;
    int* qc = qcounter + c * 16;   // 64B stride: one counter per cacheline

    for (;;) {
        int nl;
        if (lane == 0) nl = atomicAdd(qc, 4);
        nl = __builtin_amdgcn_readfirstlane(nl);
        if (nl >= cnt_c) break;
        const int nhi = (nl + 4 < cnt_c) ? nl + 4 : cnt_c;

        for (int ni = nl; ni < nhi; ++ni) {
            const int n = base + ni;

            unsigned int qp = reinterpret_cast<const unsigned int*>(qb)[(size_t)n * 64 + lane];
            float q0 = bu2f((unsigned short)(qp & 0xffffu)) * QS;
            float q1 = bu2f((unsigned short)(qp >> 16)) * QS;

            const int eoff = rowstart[n], eend = rowstart[n + 1];
            float lsum = 0.f, acc0 = 0.f, acc1 = 0.f;

            for (int p0 = eoff; p0 < eend; p0 += 16) {
                int pos = p0 + m;
                int pc = (pos < eend) ? pos : eoff;
                int sj_all = srcs[pc];   // lane m holds src for tile edge m

                // A-frag: direct bf16 load from CSR-ordered edge rows (16B/lane)
                short8 Af = *reinterpret_cast<const short8*>(eacsr + (size_t)pc * 32 + quad * 8);

                // kv prefetch: 16 coalesced 8B loads, SGPR row base via readlane
                uint2 kvr[16];
#pragma unroll
                for (int j = 0; j < 16; ++j) {
                    int sj = __builtin_amdgcn_readlane(sj_all, j);
                    kvr[j] = reinterpret_cast<const uint2*>(kvb + (size_t)(unsigned)sj * 128)[lane];
                }

#pragma unroll
                for (int nt = 0; nt < 8; ++nt) {
                    short8 Bf = *reinterpret_cast<const short8*>(&wes[(nt * 64 + lane) * 8]);
                    floatx4 C = {0.f, 0.f, 0.f, 0.f};
                    C = __builtin_amdgcn_mfma_f32_16x16x32_bf16(Af, Bf, C, 0, 0, 0);
                    int col = nt * 16 + m;
                    unsigned int d0 = (unsigned int)(unsigned short)f2bs(C[0]) |
                                      ((unsigned int)(unsigned short)f2bs(C[1]) << 16);
                    unsigned int d1 = (unsigned int)(unsigned short)f2bs(C[2]) |
                                      ((unsigned int)(unsigned short)f2bs(C[3]) << 16);
                    unsigned int* p = reinterpret_cast<unsigned int*>(&esw[col][quad * 4]);
                    p[0] = d0; p[1] = d1;   // edges quad*4..quad*4+3 of channel col
                }
                __builtin_amdgcn_wave_barrier();   // wave-local LDS: writes before reads

                // batch-read e for this lane's 2 channels, all 16 edges -> registers
                unsigned int ear[8], ebr[8];
                {
                    const unsigned int* ra = reinterpret_cast<const unsigned int*>(&esw[2 * lane][0]);
                    const unsigned int* rb = reinterpret_cast<const unsigned int*>(&esw[2 * lane + 1][0]);
#pragma unroll
                    for (int jj = 0; jj < 8; ++jj) { ear[jj] = ra[jj]; ebr[jj] = rb[jj]; }
                }

                int cnt = eend - p0; if (cnt > 16) cnt = 16;
#pragma unroll
                for (int j = 0; j < 16; ++j) {
                    unsigned int eva = ear[j >> 1], evb = ebr[j >> 1];
                    float e0 = (j & 1) ? bu2f((unsigned short)(eva >> 16))
                                       : bu2f((unsigned short)(eva & 0xffffu));
                    float e1 = (j & 1) ? bu2f((unsigned short)(evb >> 16))
                                       : bu2f((unsigned short)(evb & 0xffffu));
                    float k0 = bu2f((unsigned short)(kvr[j].x & 0xffffu));
                    float v0 = bu2f((unsigned short)(kvr[j].x >> 16));
                    float k1 = bu2f((unsigned short)(kvr[j].y & 0xffffu));
                    float v1 = bu2f((unsigned short)(kvr[j].y >> 16));
                    float pr = fmaf(k1 + e1, q1, (k0 + e0) * q0);   // pre-scaled by 0.25*log2e
                    // 3-level xor butterfly over the 8-lane head group (BitMode swizzle)
                    pr += __int_as_float(__builtin_amdgcn_ds_swizzle(__float_as_int(pr), 0x041F));
                    pr += __int_as_float(__builtin_amdgcn_ds_swizzle(__float_as_int(pr), 0x081F));
                    pr += __int_as_float(__builtin_amdgcn_ds_swizzle(__float_as_int(pr), 0x101F));
                    float w = (j < cnt) ? __builtin_amdgcn_exp2f(pr) : 0.f;
                    lsum += w;
                    acc0 = fmaf(v0 + e0, w, acc0);
                    acc1 = fmaf(v1 + e1, w, acc1);
                }
                __builtin_amdgcn_wave_barrier();   // reads before next tile's writes
            }

            float rden = 1.f / (lsum + 1e-16f);
            float attn0 = acc0 * rden, attn1 = acc1 * rden;
            float2 xv = *reinterpret_cast<const float2*>(x + (size_t)n * 128 + 2 * lane);
            unsigned int skp = reinterpret_cast<const unsigned int*>(skipb)[(size_t)n * 64 + lane];
            float pre0 = xv.x + attn0 + bu2f((unsigned short)(skp & 0xffffu));
            float pre1 = xv.y + attn1 + bu2f((unsigned short)(skp >> 16));
            float s1 = pre0 + pre1, s2 = pre0 * pre0 + pre1 * pre1;
#pragma unroll
            for (int off = 1; off < 64; off <<= 1) {
                s1 += __shfl_xor(s1, off);
                s2 += __shfl_xor(s2, off);
            }
            float mu = s1 * (1.f / 128.f);
            float var = s2 * (1.f / 128.f) - mu * mu;
            float inv = rsqrtf(var + 1e-5f);
            float2 g  = *reinterpret_cast<const float2*>(ln1g + 2 * lane);
            float2 bb = *reinterpret_cast<const float2*>(ln1b + 2 * lane);
            float h0 = (pre0 - mu) * inv * g.x + bb.x;
            float h1 = (pre1 - mu) * inv * g.y + bb.y;
            unsigned int hu = (unsigned int)(unsigned short)f2bs(h0) |
                              ((unsigned int)(unsigned short)f2bs(h1) << 16);
            reinterpret_cast<unsigned int*>(hb)[(size_t)n * 64 + lane] = hu;
        }
    }
}

// ---------------- FFN via MFMA + LN2 ----------------
__global__ __launch_bounds__(256) void k_ffn(
    const bf16* __restrict__ hb,
    const bf16* __restrict__ w1p, const float* __restrict__ b1,
    const bf16* __restrict__ w2p, const float* __restrict__ b2,
    const float* __restrict__ ln2g, const float* __restrict__ ln2b,
    float* __restrict__ out)
{
    __shared__ __align__(16) short hs[32][136];
    __shared__ __align__(16) short t1s[32][520];
    float* fs = reinterpret_cast<float*>(&t1s[0][0]);  // [32][132] after t1s is dead
    const int t = threadIdx.x;
    const int wave = t >> 6, lane = t & 63;
    const int quad = lane >> 4, m = lane & 15;
    const int n0 = blockIdx.x * 32;

    for (int idx = t; idx < 32 * 16; idx += 256) {
        int row = idx >> 4, g = idx & 15;
        int node = n0 + row;
        if (node < NN) {
            *reinterpret_cast<float4*>(&hs[row][g * 8]) =
                *reinterpret_cast<const float4*>(&hb[(size_t)node * 128 + g * 8]);
        } else {
            float4 z = {0.f, 0.f, 0.f, 0.f};
            *reinterpret_cast<float4*>(&hs[row][g * 8]) = z;
        }
    }
    __syncthreads();

    floatx4 acc1[2][8];
#pragma unroll
    for (int mt = 0; mt < 2; ++mt)
#pragma unroll
        for (int nt = 0; nt < 8; ++nt) acc1[mt][nt] = (floatx4){0.f, 0.f, 0.f, 0.f};
#pragma unroll
    for (int kstep = 0; kstep < 4; ++kstep) {
        short8 af0 = *reinterpret_cast<const short8*>(&hs[m][kstep * 32 + quad * 8]);
        short8 af1 = *reinterpret_cast<const short8*>(&hs[16 + m][kstep * 32 + quad * 8]);
#pragma unroll
        for (int nt = 0; nt < 8; ++nt) {
            short8 bf = *reinterpret_cast<const short8*>(
                reinterpret_cast<const short*>(w1p) + (((wave * 8 + nt) * 4 + kstep) * 64 + lane) * 8);
            acc1[0][nt] = __builtin_amdgcn_mfma_f32_16x16x32_bf16(af0, bf, acc1[0][nt], 0, 0, 0);
            acc1[1][nt] = __builtin_amdgcn_mfma_f32_16x16x32_bf16(af1, bf, acc1[1][nt], 0, 0, 0);
        }
    }
#pragma unroll
    for (int nt = 0; nt < 8; ++nt) {
        float bs = b1[wave * 128 + nt * 16 + m];
#pragma unroll
        for (int mt = 0; mt < 2; ++mt)
#pragma unroll
            for (int r = 0; r < 4; ++r)
                t1s[mt * 16 + quad * 4 + r][wave * 128 + nt * 16 + m] =
                    f2bs(fmaxf(acc1[mt][nt][r] + bs, 0.f));
    }
    __syncthreads();

    floatx4 acc2[2][2];
#pragma unroll
    for (int mt = 0; mt < 2; ++mt)
#pragma unroll
        for (int nt = 0; nt < 2; ++nt) acc2[mt][nt] = (floatx4){0.f, 0.f, 0.f, 0.f};
#pragma unroll
    for (int kstep = 0; kstep < 16; ++kstep) {
        short8 af0 = *reinterpret_cast<const short8*>(&t1s[m][kstep * 32 + quad * 8]);
        short8 af1 = *reinterpret_cast<const short8*>(&t1s[16 + m][kstep * 32 + quad * 8]);
#pragma unroll
        for (int nt = 0; nt < 2; ++nt) {
            short8 bf = *reinterpret_cast<const short8*>(
                reinterpret_cast<const short*>(w2p) + (((wave * 2 + nt) * 16 + kstep) * 64 + lane) * 8);
            acc2[0][nt] = __builtin_amdgcn_mfma_f32_16x16x32_bf16(af0, bf, acc2[0][nt], 0, 0, 0);
            acc2[1][nt] = __builtin_amdgcn_mfma_f32_16x16x32_bf16(af1, bf, acc2[1][nt], 0, 0, 0);
        }
    }
    __syncthreads();
#pragma unroll
    for (int nt = 0; nt < 2; ++nt) {
        int col = (wave * 2 + nt) * 16 + m;
        float bs = b2[col];
#pragma unroll
        for (int mt = 0; mt < 2; ++mt)
#pragma unroll
            for (int r = 0; r < 4; ++r)
                fs[(mt * 16 + quad * 4 + r) * 132 + col] = acc2[mt][nt][r] + bs;
    }
    __syncthreads();

    for (int rr = 0; rr < 8; ++rr) {
        int row = wave * 8 + rr;
        int node = n0 + row;
        float p0 = bs2f(hs[row][lane]) + fs[row * 132 + lane];
        float p1 = bs2f(hs[row][lane + 64]) + fs[row * 132 + lane + 64];
        float s1 = p0 + p1, s2 = p0 * p0 + p1 * p1;
#pragma unroll
        for (int off = 1; off < 64; off <<= 1) {
            s1 += __shfl_xor(s1, off);
            s2 += __shfl_xor(s2, off);
        }
        float mu = s1 * (1.f / 128.f);
        float var = s2 * (1.f / 128.f) - mu * mu;
        float inv = rsqrtf(var + 1e-5f);
        if (node < NN) {
            out[(size_t)node * 128 + lane] = (p0 - mu) * inv * ln2g[lane] + ln2b[lane];
            out[(size_t)node * 128 + lane + 64] = (p1 - mu) * inv * ln2g[lane + 64] + ln2b[lane + 64];
        }
    }
}

extern "C" void kernel_launch(void* const* d_in, const int* in_sizes, int n_in,
                              void* d_out, int out_size, void* d_ws, size_t ws_size,
                              hipStream_t stream)
{
    const float* x    = (const float*)d_in[0];
    const int*   ei   = (const int*)d_in[1];
    const float* ea   = (const float*)d_in[2];
    const float* Wq   = (const float*)d_in[3];
    const float* bq   = (const float*)d_in[4];
    const float* Wk   = (const float*)d_in[5];
    const float* bk   = (const float*)d_in[6];
    const float* Wv   = (const float*)d_in[7];
    const float* bv   = (const float*)d_in[8];
    const float* We   = (const float*)d_in[9];
    const float* Wsk  = (const float*)d_in[10];
    const float* bsk  = (const float*)d_in[11];
    const float* ln1g = (const float*)d_in[12];
    const float* ln1b = (const float*)d_in[13];
    const float* W1   = (const float*)d_in[14];
    const float* b1   = (const float*)d_in[15];
    const float* W2   = (const float*)d_in[16];
    const float* b2   = (const float*)d_in[17];
    const float* ln2g = (const float*)d_in[18];
    const float* ln2b = (const float*)d_in[19];

    char* ws = (char*)d_ws;
    size_t off = 0;
    auto alloc = [&](size_t bytes) -> void* {
        void* p = ws + off;
        off += (bytes + 255) & ~(size_t)255;
        return p;
    };
    int*   flag     = (int*)alloc(256);
    int*   qcounter = (int*)alloc((size_t)NQC * 16 * 4);   // 64 counters, 64B stride
    int*   deg      = (int*)alloc((size_t)NN * 4);
    int*   cursor   = (int*)alloc((size_t)NN * 4);
    int*   rowstart = (int*)alloc((size_t)(NN + 1) * 4);
    int*   srcs     = (int*)alloc((size_t)EE * 4);
    int*   eids     = (int*)alloc((size_t)EE * 4);
    short* eacsr    = (short*)alloc((size_t)EE * 32 * 2);  // CSR-ordered bf16 edge rows
    bf16*  qb       = (bf16*)alloc((size_t)NN * 128 * 2);
    unsigned int* kvb = (unsigned int*)alloc((size_t)NN * 128 * 4);
    bf16*  skipb    = (bf16*)alloc((size_t)NN * 128 * 2);
    bf16*  hb       = (bf16*)alloc((size_t)NN * 128 * 2);
    bf16*  wqp      = (bf16*)alloc((size_t)16384 * 2);
    bf16*  wkp      = (bf16*)alloc((size_t)16384 * 2);
    bf16*  wvp      = (bf16*)alloc((size_t)16384 * 2);
    bf16*  wskp     = (bf16*)alloc((size_t)16384 * 2);
    bf16*  w1p      = (bf16*)alloc((size_t)65536 * 2);
    bf16*  w2p      = (bf16*)alloc((size_t)65536 * 2);
    bf16*  wep      = (bf16*)alloc((size_t)4096 * 2);

    hipMemsetAsync(deg, 0, (size_t)NN * 4, stream);
    hipMemsetAsync(cursor, 0, (size_t)NN * 4, stream);
    hipMemsetAsync(qcounter, 0, (size_t)NQC * 16 * 4, stream);

    k_packall<<<785, 256, 0, stream>>>(
        Wq, Wk, Wv, Wsk, W1, W2, We, wqp, wkp, wvp, wskp, w1p, w2p, wep, ei, flag);
    k_hist<<<(EE / 2 + 255) / 256, 256, 0, stream>>>(ei, flag, deg);
    k_proj<<<(NN + 31) / 32, 256, 0, stream>>>(x, wqp, wkp, wvp, wskp,
                                               bq, bk, bv, bsk, qb, kvb, skipb);
    k_scan<<<1, 1024, 0, stream>>>(deg, rowstart);
    k_scatter<<<(EE + 255) / 256, 256, 0, stream>>>(ei, flag, rowstart, cursor,
                                                    srcs, eids);
    k_gather<<<(EE * 4 + 255) / 256, 256, 0, stream>>>(eids, ea, eacsr);
    k_attn<<<1536, 256, 0, stream>>>(x, eacsr, wep, qb, kvb, skipb,
                                     rowstart, srcs, ln1g, ln1b, qcounter, hb);
    k_ffn<<<(NN + 31) / 32, 256, 0, stream>>>(hb, w1p, b1, w2p, b2, ln2g, ln2b, (float*)d_out);
}

// Round 7
// 547.745 us; speedup vs baseline: 1.1581x; 1.0566x over previous
//
#include <hip/hip_runtime.h>
#include <hip/hip_bf16.h>

using bf16 = __hip_bfloat16;
typedef __attribute__((ext_vector_type(8))) short short8;
typedef __attribute__((ext_vector_type(4))) float floatx4;

#define NN 50000
#define EE 800000
#define DD 128
#define HH 8
#define CC 16
#define EDD 32
#define DF 512
#define NQC 64      // partitioned queue counters
#define PART 782    // ceil(NN/NQC)

__device__ __forceinline__ float b2f(bf16 v) { return __bfloat162float(v); }
__device__ __forceinline__ float bs2f(short s) {
    bf16 h = *reinterpret_cast<bf16*>(&s);
    return __bfloat162float(h);
}
__device__ __forceinline__ float bu2f(unsigned short s) {
    unsigned int u = ((unsigned int)s) << 16;
    return *reinterpret_cast<float*>(&u);
}
__device__ __forceinline__ short f2bs(float v) {
    bf16 h = __float2bfloat16(v);
    return *reinterpret_cast<short*>(&h);
}

__device__ __forceinline__ int clampn(int v)
{
    return (v < 0) ? 0 : (v >= NN ? NN - 1 : v);
}

// ---- pack ALL fp32 weights [K][N] into per-lane MFMA B-frag layout (bf16) ----
// + zero deg/cursor/qcounter (replaces 3 hipMemsets)
// + block 784 thread 0: edge_index width detection (int64 has zero high-words)
__global__ void k_packall(const float* __restrict__ Wq, const float* __restrict__ Wk,
                          const float* __restrict__ Wv, const float* __restrict__ Wsk,
                          const float* __restrict__ W1, const float* __restrict__ W2,
                          const float* __restrict__ We,
                          bf16* __restrict__ wqp, bf16* __restrict__ wkp,
                          bf16* __restrict__ wvp, bf16* __restrict__ wskp,
                          bf16* __restrict__ w1p, bf16* __restrict__ w2p,
                          bf16* __restrict__ wep,
                          const int* __restrict__ ei, int* __restrict__ flag,
                          int* __restrict__ deg, int* __restrict__ cursor,
                          int* __restrict__ qcounter)
{
    int idx = blockIdx.x * 256 + threadIdx.x;
    // fused zeroing: deg[0..NN), cursor[0..NN), qcounter[0..NQC*16)
    if (idx < NN) deg[idx] = 0;
    else if (idx < 2 * NN) cursor[idx - NN] = 0;
    else if (idx < 2 * NN + NQC * 16) qcounter[idx - 2 * NN] = 0;

    const float* W; bf16* out; int ksteps, N, local;
    if (idx < 65536) {
        int wsel = idx >> 14; local = idx & 16383;
        W   = (wsel == 0) ? Wq  : (wsel == 1) ? Wk  : (wsel == 2) ? Wv  : Wsk;
        out = (wsel == 0) ? wqp : (wsel == 1) ? wkp : (wsel == 2) ? wvp : wskp;
        ksteps = 4; N = 128;
    } else if (idx < 131072) { local = idx - 65536;  W = W1; out = w1p; ksteps = 4;  N = 512; }
    else if (idx < 196608)   { local = idx - 131072; W = W2; out = w2p; ksteps = 16; N = 128; }
    else if (idx < 200704)   { local = idx - 196608; W = We; out = wep; ksteps = 1;  N = 128; }
    else {
        if (idx == 200704) {   // block 784, thread 0: detect
            int all0 = 1;
            for (int i = 0; i < 16; ++i) all0 &= (ei[2 * i + 1] == 0);
            flag[0] = all0;    // 1 => int64 layout, 0 => int32
        }
        return;
    }
    int j = local & 7, lane = (local >> 3) & 63, rest = local >> 9;
    int kstep = rest % ksteps, ntile = rest / ksteps;
    int quad = lane >> 4, m = lane & 15;
    int k = kstep * 32 + quad * 8 + j;
    int n = ntile * 16 + m;
    out[local] = __float2bfloat16(W[(size_t)k * N + n]);
}

// ---------------- projections via MFMA: q, k|v packed, skip(+x) ----------------
__global__ __launch_bounds__(256) void k_proj(
    const float* __restrict__ x,
    const bf16* __restrict__ wqp, const bf16* __restrict__ wkp,
    const bf16* __restrict__ wvp, const bf16* __restrict__ wskp,
    const float* __restrict__ bq, const float* __restrict__ bk,
    const float* __restrict__ bv, const float* __restrict__ bsk,
    bf16* __restrict__ qb, unsigned int* __restrict__ kvb,
    bf16* __restrict__ skipb)
{
    __shared__ __align__(16) short xs[32][136];
    __shared__ __align__(16) short os[32][520];
    const int t = threadIdx.x;
    const int wave = t >> 6, lane = t & 63;
    const int quad = lane >> 4, m = lane & 15;
    const int n0 = blockIdx.x * 32;

    for (int idx = t; idx < 32 * 32; idx += 256) {
        int row = idx >> 5, g = idx & 31;
        int node = n0 + row;
        float4 xv = {0.f, 0.f, 0.f, 0.f};
        if (node < NN) xv = *reinterpret_cast<const float4*>(&x[(size_t)node * 128 + g * 4]);
        short4 s4;
        s4.x = f2bs(xv.x); s4.y = f2bs(xv.y); s4.z = f2bs(xv.z); s4.w = f2bs(xv.w);
        *reinterpret_cast<short4*>(&xs[row][g * 4]) = s4;
    }
    __syncthreads();

    const bf16* Wp = (wave == 0) ? wqp : (wave == 1) ? wkp : (wave == 2) ? wvp : wskp;
    const float* bias = (wave == 0) ? bq : (wave == 1) ? bk : (wave == 2) ? bv : bsk;

    floatx4 acc[2][8];
#pragma unroll
    for (int mt = 0; mt < 2; ++mt)
#pragma unroll
        for (int nt = 0; nt < 8; ++nt) acc[mt][nt] = (floatx4){0.f, 0.f, 0.f, 0.f};

#pragma unroll
    for (int kstep = 0; kstep < 4; ++kstep) {
        short8 af0 = *reinterpret_cast<const short8*>(&xs[m][kstep * 32 + quad * 8]);
        short8 af1 = *reinterpret_cast<const short8*>(&xs[16 + m][kstep * 32 + quad * 8]);
#pragma unroll
        for (int nt = 0; nt < 8; ++nt) {
            short8 bf = *reinterpret_cast<const short8*>(
                reinterpret_cast<const short*>(Wp) + ((nt * 4 + kstep) * 64 + lane) * 8);
            acc[0][nt] = __builtin_amdgcn_mfma_f32_16x16x32_bf16(af0, bf, acc[0][nt], 0, 0, 0);
            acc[1][nt] = __builtin_amdgcn_mfma_f32_16x16x32_bf16(af1, bf, acc[1][nt], 0, 0, 0);
        }
    }
#pragma unroll
    for (int nt = 0; nt < 8; ++nt) {
        float bs = bias[nt * 16 + m];
#pragma unroll
        for (int mt = 0; mt < 2; ++mt)
#pragma unroll
            for (int r = 0; r < 4; ++r)
                os[mt * 16 + quad * 4 + r][wave * 128 + nt * 16 + m] = f2bs(acc[mt][nt][r] + bs);
    }
    __syncthreads();
    // output: q (bf16), skip+x (bf16), kv packed as uint (k low16 | v high16)
    for (int idx = t; idx < 32 * 64; idx += 256) {
        int row = idx >> 6, c = idx & 63;
        int node = n0 + row;
        if (node >= NN) continue;
        unsigned int qu  = *reinterpret_cast<const unsigned int*>(&os[row][2 * c]);
        unsigned int ku  = *reinterpret_cast<const unsigned int*>(&os[row][128 + 2 * c]);
        unsigned int vu  = *reinterpret_cast<const unsigned int*>(&os[row][256 + 2 * c]);
        float sk0 = bs2f(os[row][384 + 2 * c])     + bs2f(xs[row][2 * c]);
        float sk1 = bs2f(os[row][384 + 2 * c + 1]) + bs2f(xs[row][2 * c + 1]);
        unsigned int sku = (unsigned int)(unsigned short)f2bs(sk0) |
                           ((unsigned int)(unsigned short)f2bs(sk1) << 16);
        reinterpret_cast<unsigned int*>(qb)[(size_t)node * 64 + c] = qu;
        reinterpret_cast<unsigned int*>(skipb)[(size_t)node * 64 + c] = sku;
        uint2 kv;
        kv.x = (ku & 0xffffu) | (vu << 16);          // ch 2c  : k|v
        kv.y = (ku >> 16) | (vu & 0xffff0000u);      // ch 2c+1: k|v
        reinterpret_cast<uint2*>(kvb)[(size_t)node * 64 + c] = kv;
    }
}

// ---------------- CSR build ----------------
__global__ void k_hist(const int* __restrict__ ei, const int* __restrict__ flag,
                       int* __restrict__ deg)
{
    int tt = blockIdx.x * 256 + threadIdx.x;
    int i0 = tt * 2;
    if (i0 >= EE) return;
    int d0, d1;
    if (flag[0]) {
        int4 v = *reinterpret_cast<const int4*>(&ei[2 * EE + 2 * i0]);
        d0 = v.x; d1 = v.z;
    } else {
        int2 v = *reinterpret_cast<const int2*>(&ei[EE + i0]);
        d0 = v.x; d1 = v.y;
    }
    atomicAdd(&deg[clampn(d0)], 1);
    atomicAdd(&deg[clampn(d1)], 1);
}

__global__ __launch_bounds__(1024) void k_scan(const int* __restrict__ deg,
                                               int* __restrict__ rowstart)
{
    __shared__ int s[1024];
    const int t = threadIdx.x;
    const int CH = 49;
    int base = t * CH;
    int sum = 0;
    for (int i = 0; i < CH; i++) {
        int idx = base + i;
        if (idx < NN) sum += deg[idx];
    }
    s[t] = sum;
    __syncthreads();
    int own = sum;
    for (int off = 1; off < 1024; off <<= 1) {
        int v = (t >= off) ? s[t - off] : 0;
        __syncthreads();
        s[t] += v;
        __syncthreads();
    }
    int run = s[t] - own;
    for (int i = 0; i < CH; i++) {
        int idx = base + i;
        if (idx < NN) {
            rowstart[idx] = run;
            run += deg[idx];
        }
    }
    if (t == 0) rowstart[NN] = EE;
}

// scatter: permutation only — one scattered 8B store {src, eid} per edge
__global__ void k_scatter(const int* __restrict__ ei, const int* __restrict__ flag,
                          const int* __restrict__ rowstart,
                          int* __restrict__ cursor, int2* __restrict__ srcid)
{
    int i = blockIdx.x * 256 + threadIdx.x;
    if (i >= EE) return;
    int is64 = flag[0];
    int d = clampn(is64 ? ei[2 * EE + 2 * i] : ei[EE + i]);
    int s = clampn(is64 ? ei[2 * i] : ei[i]);
    int pos = rowstart[d] + atomicAdd(&cursor[d], 1);
    srcid[pos] = make_int2(s, i);
}

// -------- fused attention: PERSISTENT WAVES, 64 partitioned queue counters --------
// block = 256 threads = 4 waves; wave g pops node batches (4) from counter g&63.
// lane owns channels 2*lane, 2*lane+1 (head = lane>>3, 8 lanes per head).
// A-frag read directly from edge_attr (fp32, full-line random reads) — no eacsr.
__global__ __launch_bounds__(256) void k_attn(
    const float* __restrict__ edge_attr, const bf16* __restrict__ wep,
    const bf16* __restrict__ qb, const unsigned int* __restrict__ kvb,
    const bf16* __restrict__ skipb,
    const int* __restrict__ rowstart, const int2* __restrict__ srcid,
    const float* __restrict__ ln1g, const float* __restrict__ ln1b,
    int* __restrict__ qcounter, bf16* __restrict__ hb)
{
    // es transposed: [channel][edge] with stride 18 shorts (36B) per channel row
    __shared__ __align__(16) short es[4][128][18];
    __shared__ __align__(16) short wes[4096];
    const int t = threadIdx.x;
    const int wave = t >> 6, lane = t & 63;
    const int quad = lane >> 4, m = lane & 15;

    // stage We fragments once per block (8 ntiles x 64 lanes x 8 bf16 = 8KB)
    for (int idx = t; idx < 512; idx += 256)
        *reinterpret_cast<short8*>(&wes[idx * 8]) =
            *reinterpret_cast<const short8*>(reinterpret_cast<const short*>(wep) + idx * 8);
    __syncthreads();   // only barrier in the kernel

    short (*esw)[18] = es[wave];
    const float QS = 0.3606737602f;   // 0.25 * log2(e)

    const int gw = blockIdx.x * 4 + wave;
    const int c  = gw & (NQC - 1);
    const int base = c * PART;
    const int cnt_c = (NN - base < PART) ? (NN - base) : PART;
    int* qc = qcounter + c * 16;   // 64B stride: one counter per cacheline

    for (;;) {
        int nl;
        if (lane == 0) nl = atomicAdd(qc, 4);
        nl = __builtin_amdgcn_readfirstlane(nl);
        if (nl >= cnt_c) break;
        const int nhi = (nl + 4 < cnt_c) ? nl + 4 : cnt_c;

        for (int ni = nl; ni < nhi; ++ni) {
            const int n = base + ni;

            unsigned int qp = reinterpret_cast<const unsigned int*>(qb)[(size_t)n * 64 + lane];
            float q0 = bu2f((unsigned short)(qp & 0xffffu)) * QS;
            float q1 = bu2f((unsigned short)(qp >> 16)) * QS;

            const int eoff = rowstart[n], eend = rowstart[n + 1];
            float lsum = 0.f, acc0 = 0.f, acc1 = 0.f;

            for (int p0 = eoff; p0 < eend; p0 += 16) {
                int pos = p0 + m;
                int pc = (pos < eend) ? pos : eoff;
                int2 se = srcid[pc];   // lane m holds {src, eid} for tile edge m

                // A-frag: direct fp32 loads from edge_attr (full lines consumed by 4 quads)
                const float* arow = edge_attr + (size_t)se.y * 32 + quad * 8;
                float4 a0 = *reinterpret_cast<const float4*>(arow);
                float4 a1 = *reinterpret_cast<const float4*>(arow + 4);

                // kv prefetch: 16 coalesced 8B loads, SGPR row base via readlane
                uint2 kvr[16];
#pragma unroll
                for (int j = 0; j < 16; ++j) {
                    int sj = __builtin_amdgcn_readlane(se.x, j);
                    kvr[j] = reinterpret_cast<const uint2*>(kvb + (size_t)(unsigned)sj * 128)[lane];
                }

                short8 Af;
                Af[0] = f2bs(a0.x); Af[1] = f2bs(a0.y); Af[2] = f2bs(a0.z); Af[3] = f2bs(a0.w);
                Af[4] = f2bs(a1.x); Af[5] = f2bs(a1.y); Af[6] = f2bs(a1.z); Af[7] = f2bs(a1.w);
#pragma unroll
                for (int nt = 0; nt < 8; ++nt) {
                    short8 Bf = *reinterpret_cast<const short8*>(&wes[(nt * 64 + lane) * 8]);
                    floatx4 C = {0.f, 0.f, 0.f, 0.f};
                    C = __builtin_amdgcn_mfma_f32_16x16x32_bf16(Af, Bf, C, 0, 0, 0);
                    int col = nt * 16 + m;
                    unsigned int d0 = (unsigned int)(unsigned short)f2bs(C[0]) |
                                      ((unsigned int)(unsigned short)f2bs(C[1]) << 16);
                    unsigned int d1 = (unsigned int)(unsigned short)f2bs(C[2]) |
                                      ((unsigned int)(unsigned short)f2bs(C[3]) << 16);
                    unsigned int* p = reinterpret_cast<unsigned int*>(&esw[col][quad * 4]);
                    p[0] = d0; p[1] = d1;   // edges quad*4..quad*4+3 of channel col
                }
                __builtin_amdgcn_wave_barrier();   // wave-local LDS: writes before reads

                // batch-read e for this lane's 2 channels, all 16 edges -> registers
                unsigned int ear[8], ebr[8];
                {
                    const unsigned int* ra = reinterpret_cast<const unsigned int*>(&esw[2 * lane][0]);
                    const unsigned int* rb = reinterpret_cast<const unsigned int*>(&esw[2 * lane + 1][0]);
#pragma unroll
                    for (int jj = 0; jj < 8; ++jj) { ear[jj] = ra[jj]; ebr[jj] = rb[jj]; }
                }

                int cnt = eend - p0; if (cnt > 16) cnt = 16;
#pragma unroll
                for (int j = 0; j < 16; ++j) {
                    unsigned int eva = ear[j >> 1], evb = ebr[j >> 1];
                    float e0 = (j & 1) ? bu2f((unsigned short)(eva >> 16))
                                       : bu2f((unsigned short)(eva & 0xffffu));
                    float e1 = (j & 1) ? bu2f((unsigned short)(evb >> 16))
                                       : bu2f((unsigned short)(evb & 0xffffu));
                    float k0 = bu2f((unsigned short)(kvr[j].x & 0xffffu));
                    float v0 = bu2f((unsigned short)(kvr[j].x >> 16));
                    float k1 = bu2f((unsigned short)(kvr[j].y & 0xffffu));
                    float v1 = bu2f((unsigned short)(kvr[j].y >> 16));
                    float pr = fmaf(k1 + e1, q1, (k0 + e0) * q0);   // pre-scaled by 0.25*log2e
                    // 3-level xor butterfly over the 8-lane head group (BitMode swizzle)
                    pr += __int_as_float(__builtin_amdgcn_ds_swizzle(__float_as_int(pr), 0x041F));
                    pr += __int_as_float(__builtin_amdgcn_ds_swizzle(__float_as_int(pr), 0x081F));
                    pr += __int_as_float(__builtin_amdgcn_ds_swizzle(__float_as_int(pr), 0x101F));
                    float w = (j < cnt) ? __builtin_amdgcn_exp2f(pr) : 0.f;
                    lsum += w;
                    acc0 = fmaf(v0 + e0, w, acc0);
                    acc1 = fmaf(v1 + e1, w, acc1);
                }
                __builtin_amdgcn_wave_barrier();   // reads before next tile's writes
            }

            float rden = 1.f / (lsum + 1e-16f);
            float attn0 = acc0 * rden, attn1 = acc1 * rden;
            unsigned int skp = reinterpret_cast<const unsigned int*>(skipb)[(size_t)n * 64 + lane];
            float pre0 = attn0 + bu2f((unsigned short)(skp & 0xffffu));   // skipb = skip + x
            float pre1 = attn1 + bu2f((unsigned short)(skp >> 16));
            float s1 = pre0 + pre1, s2 = pre0 * pre0 + pre1 * pre1;
#pragma unroll
            for (int off = 1; off < 64; off <<= 1) {
                s1 += __shfl_xor(s1, off);
                s2 += __shfl_xor(s2, off);
            }
            float mu = s1 * (1.f / 128.f);
            float var = s2 * (1.f / 128.f) - mu * mu;
            float inv = rsqrtf(var + 1e-5f);
            float2 g  = *reinterpret_cast<const float2*>(ln1g + 2 * lane);
            float2 bb = *reinterpret_cast<const float2*>(ln1b + 2 * lane);
            float h0 = (pre0 - mu) * inv * g.x + bb.x;
            float h1 = (pre1 - mu) * inv * g.y + bb.y;
            unsigned int hu = (unsigned int)(unsigned short)f2bs(h0) |
                              ((unsigned int)(unsigned short)f2bs(h1) << 16);
            reinterpret_cast<unsigned int*>(hb)[(size_t)n * 64 + lane] = hu;
        }
    }
}

// ---------------- FFN via MFMA + LN2 ----------------
__global__ __launch_bounds__(256) void k_ffn(
    const bf16* __restrict__ hb,
    const bf16* __restrict__ w1p, const float* __restrict__ b1,
    const bf16* __restrict__ w2p, const float* __restrict__ b2,
    const float* __restrict__ ln2g, const float* __restrict__ ln2b,
    float* __restrict__ out)
{
    __shared__ __align__(16) short hs[32][136];
    __shared__ __align__(16) short t1s[32][520];
    float* fs = reinterpret_cast<float*>(&t1s[0][0]);  // [32][132] after t1s is dead
    const int t = threadIdx.x;
    const int wave = t >> 6, lane = t & 63;
    const int quad = lane >> 4, m = lane & 15;
    const int n0 = blockIdx.x * 32;

    for (int idx = t; idx < 32 * 16; idx += 256) {
        int row = idx >> 4, g = idx & 15;
        int node = n0 + row;
        if (node < NN) {
            *reinterpret_cast<float4*>(&hs[row][g * 8]) =
                *reinterpret_cast<const float4*>(&hb[(size_t)node * 128 + g * 8]);
        } else {
            float4 z = {0.f, 0.f, 0.f, 0.f};
            *reinterpret_cast<float4*>(&hs[row][g * 8]) = z;
        }
    }
    __syncthreads();

    floatx4 acc1[2][8];
#pragma unroll
    for (int mt = 0; mt < 2; ++mt)
#pragma unroll
        for (int nt = 0; nt < 8; ++nt) acc1[mt][nt] = (floatx4){0.f, 0.f, 0.f, 0.f};
#pragma unroll
    for (int kstep = 0; kstep < 4; ++kstep) {
        short8 af0 = *reinterpret_cast<const short8*>(&hs[m][kstep * 32 + quad * 8]);
        short8 af1 = *reinterpret_cast<const short8*>(&hs[16 + m][kstep * 32 + quad * 8]);
#pragma unroll
        for (int nt = 0; nt < 8; ++nt) {
            short8 bf = *reinterpret_cast<const short8*>(
                reinterpret_cast<const short*>(w1p) + (((wave * 8 + nt) * 4 + kstep) * 64 + lane) * 8);
            acc1[0][nt] = __builtin_amdgcn_mfma_f32_16x16x32_bf16(af0, bf, acc1[0][nt], 0, 0, 0);
            acc1[1][nt] = __builtin_amdgcn_mfma_f32_16x16x32_bf16(af1, bf, acc1[1][nt], 0, 0, 0);
        }
    }
#pragma unroll
    for (int nt = 0; nt < 8; ++nt) {
        float bs = b1[wave * 128 + nt * 16 + m];
#pragma unroll
        for (int mt = 0; mt < 2; ++mt)
#pragma unroll
            for (int r = 0; r < 4; ++r)
                t1s[mt * 16 + quad * 4 + r][wave * 128 + nt * 16 + m] =
                    f2bs(fmaxf(acc1[mt][nt][r] + bs, 0.f));
    }
    __syncthreads();

    floatx4 acc2[2][2];
#pragma unroll
    for (int mt = 0; mt < 2; ++mt)
#pragma unroll
        for (int nt = 0; nt < 2; ++nt) acc2[mt][nt] = (floatx4){0.f, 0.f, 0.f, 0.f};
#pragma unroll
    for (int kstep = 0; kstep < 16; ++kstep) {
        short8 af0 = *reinterpret_cast<const short8*>(&t1s[m][kstep * 32 + quad * 8]);
        short8 af1 = *reinterpret_cast<const short8*>(&t1s[16 + m][kstep * 32 + quad * 8]);
#pragma unroll
        for (int nt = 0; nt < 2; ++nt) {
            short8 bf = *reinterpret_cast<const short8*>(
                reinterpret_cast<const short*>(w2p) + (((wave * 2 + nt) * 16 + kstep) * 64 + lane) * 8);
            acc2[0][nt] = __builtin_amdgcn_mfma_f32_16x16x32_bf16(af0, bf, acc2[0][nt], 0, 0, 0);
            acc2[1][nt] = __builtin_amdgcn_mfma_f32_16x16x32_bf16(af1, bf, acc2[1][nt], 0, 0, 0);
        }
    }
    __syncthreads();
#pragma unroll
    for (int nt = 0; nt < 2; ++nt) {
        int col = (wave * 2 + nt) * 16 + m;
        float bs = b2[col];
#pragma unroll
        for (int mt = 0; mt < 2; ++mt)
#pragma unroll
            for (int r = 0; r < 4; ++r)
                fs[(mt * 16 + quad * 4 + r) * 132 + col] = acc2[mt][nt][r] + bs;
    }
    __syncthreads();

    for (int rr = 0; rr < 8; ++rr) {
        int row = wave * 8 + rr;
        int node = n0 + row;
        float p0 = bs2f(hs[row][lane]) + fs[row * 132 + lane];
        float p1 = bs2f(hs[row][lane + 64]) + fs[row * 132 + lane + 64];
        float s1 = p0 + p1, s2 = p0 * p0 + p1 * p1;
#pragma unroll
        for (int off = 1; off < 64; off <<= 1) {
            s1 += __shfl_xor(s1, off);
            s2 += __shfl_xor(s2, off);
        }
        float mu = s1 * (1.f / 128.f);
        float var = s2 * (1.f / 128.f) - mu * mu;
        float inv = rsqrtf(var + 1e-5f);
        if (node < NN) {
            out[(size_t)node * 128 + lane] = (p0 - mu) * inv * ln2g[lane] + ln2b[lane];
            out[(size_t)node * 128 + lane + 64] = (p1 - mu) * inv * ln2g[lane + 64] + ln2b[lane + 64];
        }
    }
}

extern "C" void kernel_launch(void* const* d_in, const int* in_sizes, int n_in,
                              void* d_out, int out_size, void* d_ws, size_t ws_size,
                              hipStream_t stream)
{
    const float* x    = (const float*)d_in[0];
    const int*   ei   = (const int*)d_in[1];
    const float* ea   = (const float*)d_in[2];
    const float* Wq   = (const float*)d_in[3];
    const float* bq   = (const float*)d_in[4];
    const float* Wk   = (const float*)d_in[5];
    const float* bk   = (const float*)d_in[6];
    const float* Wv   = (const float*)d_in[7];
    const float* bv   = (const float*)d_in[8];
    const float* We   = (const float*)d_in[9];
    const float* Wsk  = (const float*)d_in[10];
    const float* bsk  = (const float*)d_in[11];
    const float* ln1g = (const float*)d_in[12];
    const float* ln1b = (const float*)d_in[13];
    const float* W1   = (const float*)d_in[14];
    const float* b1   = (const float*)d_in[15];
    const float* W2   = (const float*)d_in[16];
    const float* b2   = (const float*)d_in[17];
    const float* ln2g = (const float*)d_in[18];
    const float* ln2b = (const float*)d_in[19];

    char* ws = (char*)d_ws;
    size_t off = 0;
    auto alloc = [&](size_t bytes) -> void* {
        void* p = ws + off;
        off += (bytes + 255) & ~(size_t)255;
        return p;
    };
    int*   flag     = (int*)alloc(256);
    int*   qcounter = (int*)alloc((size_t)NQC * 16 * 4);   // 64 counters, 64B stride
    int*   deg      = (int*)alloc((size_t)NN * 4);
    int*   cursor   = (int*)alloc((size_t)NN * 4);
    int*   rowstart = (int*)alloc((size_t)(NN + 1) * 4);
    int2*  srcid    = (int2*)alloc((size_t)EE * 8);
    bf16*  qb       = (bf16*)alloc((size_t)NN * 128 * 2);
    unsigned int* kvb = (unsigned int*)alloc((size_t)NN * 128 * 4);
    bf16*  skipb    = (bf16*)alloc((size_t)NN * 128 * 2);
    bf16*  hb       = (bf16*)alloc((size_t)NN * 128 * 2);
    bf16*  wqp      = (bf16*)alloc((size_t)16384 * 2);
    bf16*  wkp      = (bf16*)alloc((size_t)16384 * 2);
    bf16*  wvp      = (bf16*)alloc((size_t)16384 * 2);
    bf16*  wskp     = (bf16*)alloc((size_t)16384 * 2);
    bf16*  w1p      = (bf16*)alloc((size_t)65536 * 2);
    bf16*  w2p      = (bf16*)alloc((size_t)65536 * 2);
    bf16*  wep      = (bf16*)alloc((size_t)4096 * 2);

    k_packall<<<785, 256, 0, stream>>>(
        Wq, Wk, Wv, Wsk, W1, W2, We, wqp, wkp, wvp, wskp, w1p, w2p, wep,
        ei, flag, deg, cursor, qcounter);
    k_hist<<<(EE / 2 + 255) / 256, 256, 0, stream>>>(ei, flag, deg);
    k_proj<<<(NN + 31) / 32, 256, 0, stream>>>(x, wqp, wkp, wvp, wskp,
                                               bq, bk, bv, bsk, qb, kvb, skipb);
    k_scan<<<1, 1024, 0, stream>>>(deg, rowstart);
    k_scatter<<<(EE + 255) / 256, 256, 0, stream>>>(ei, flag, rowstart, cursor, srcid);
    k_attn<<<1536, 256, 0, stream>>>(ea, wep, qb, kvb, skipb,
                                     rowstart, srcid, ln1g, ln1b, qcounter, hb);
    k_ffn<<<(NN + 31) / 32, 256, 0, stream>>>(hb, w1p, b1, w2p, b2, ln2g, ln2b, (float*)d_out);
}